// Round 4
// baseline (2879.927 us; speedup 1.0000x reference)
//
#include <hip/hip_runtime.h>

#define N_ROWS 131072
#define DIM    128
#define QST    4
#define KC     1024
#define BM     128     // rows per workgroup
#define CCHUNK 128     // codes per register-tile pass
#define NTH    256
#define EPS    4e-3f   // certified fp32 argmin margin (>=4x realistic worst-case err)
#define FLAGB  (1 << 16)
#define A_FLOATS (DIM * BM)   // 16384 floats = 64 KB

// Transpose codebooks -> ET[q][d][k]; c[q][k] = ||E_k||^2 in fp64 + fp32 copy
__global__ void k_prep(const float* __restrict__ cb, float* __restrict__ ET,
                       double* __restrict__ cvec64, float* __restrict__ cvec32) {
  int gid = blockIdx.x * blockDim.x + threadIdx.x;
  if (gid >= QST * KC) return;
  int q = gid >> 10, k = gid & (KC - 1);
  const float* e = cb + ((size_t)q * KC + k) * DIM;
  double s = 0.0;
  for (int d = 0; d < DIM; d++) {
    float v = e[d];
    s = fma((double)v, (double)v, s);
    ET[((size_t)q * DIM + d) * KC + k] = v;
  }
  cvec64[q * KC + k] = s;
  cvec32[q * KC + k] = (float)s;
}

__global__ __launch_bounds__(NTH, 2) void k_stage(
    int st, const float* __restrict__ rin, float* __restrict__ rout,
    const float* __restrict__ cb, const float* __restrict__ ET,
    const double* __restrict__ cvec64, const float* __restrict__ cvec32,
    float* __restrict__ oidx, float* __restrict__ lpart)
{
  extern __shared__ float smem[];
  float*  A     = smem;                                   // [DIM][BM] 64 KB
  int*    idxs  = (int*)(smem + A_FLOATS);                // 128 ints
  double* redd  = (double*)(smem + A_FLOATS + 128);       // 4 doubles (8B aligned)
  int*    redi  = (int*)(smem + A_FLOATS + 136);          // 4 ints
  float*  redf  = smem + A_FLOATS + 140;                  // 4 floats
  int*    flags = (int*)(smem + A_FLOATS + 144);          // 4 ints

  const int tid = threadIdx.x;
  const int tx = tid & 15, ty = tid >> 4;
  const int lane = tid & 63, wv = tid >> 6;
  const size_t rowbase = (size_t)blockIdx.x * BM;

  // ---- A staging: read residual rows (natural layout), transpose into LDS
  {
    int row = tid >> 1, h = tid & 1;
    const float4* src = (const float4*)(rin + (rowbase + row) * DIM + h * 64);
    #pragma unroll
    for (int i = 0; i < 16; i++) {
      float4 v = src[i];
      int d0 = h * 64 + i * 4;
      A[(d0 + 0) * BM + row] = v.x;
      A[(d0 + 1) * BM + row] = v.y;
      A[(d0 + 2) * BM + row] = v.z;
      A[(d0 + 3) * BM + row] = v.w;
    }
  }
  __syncthreads();

  const float*  ETq  = ET + (size_t)st * DIM * KC;
  const double* cq64 = cvec64 + st * KC;
  const float*  cq32 = cvec32 + st * KC;
  const float*  Eq   = cb + (size_t)st * KC * DIM;

  float b1[8], b2[8];
  int   i1[8];
  #pragma unroll
  for (int i = 0; i < 8; i++) { b1[i] = 3.4e38f; b2[i] = 3.4e38f; i1[i] = 0; }

  // ---- main loop: B straight from global (L1/L2-resident, lanes share lines)
  for (int cc = 0; cc < 8; cc++) {
    float acc[8][8];
    #pragma unroll
    for (int r = 0; r < 8; r++)
      #pragma unroll
      for (int j = 0; j < 8; j++) acc[r][j] = 0.f;

    const float* Bp = ETq + cc * CCHUNK + tx * 4;
    #pragma unroll 4
    for (int d = 0; d < DIM; d++) {
      const float* Arow = A + d * BM + ty * 8;
      float4 a0 = *(const float4*)(Arow);
      float4 a1 = *(const float4*)(Arow + 4);
      const float* Brow = Bp + (size_t)d * KC;
      float4 b0 = *(const float4*)(Brow);
      float4 bb = *(const float4*)(Brow + 64);
      float av[8] = {a0.x, a0.y, a0.z, a0.w, a1.x, a1.y, a1.z, a1.w};
      float bv[8] = {b0.x, b0.y, b0.z, b0.w, bb.x, bb.y, bb.z, bb.w};
      #pragma unroll
      for (int r = 0; r < 8; r++)
        #pragma unroll
        for (int j = 0; j < 8; j++)
          acc[r][j] = fmaf(av[r], bv[j], acc[r][j]);
    }

    // ---- scores; per-row top-2 (thread-local codes)
    float4 c0 = *(const float4*)(cq32 + cc * CCHUNK + tx * 4);
    float4 c1 = *(const float4*)(cq32 + cc * CCHUNK + 64 + tx * 4);
    float cv[8] = {c0.x, c0.y, c0.z, c0.w, c1.x, c1.y, c1.z, c1.w};
    #pragma unroll
    for (int r = 0; r < 8; r++) {
      #pragma unroll
      for (int j = 0; j < 8; j++) {
        float sc = fmaf(-2.f, acc[r][j], cv[j]);
        int code = cc * CCHUNK + ((j < 4) ? (tx * 4 + j) : (64 + tx * 4 + (j - 4)));
        if (sc < b1[r]) { b2[r] = b1[r]; b1[r] = sc; i1[r] = code; }
        else            { b2[r] = fminf(b2[r], sc); }   // sc==b1 -> gap 0 -> rescue
      }
    }
  }

  // ---- cross-tx top-2 reduce (16 threads share each row)
  #pragma unroll
  for (int m = 1; m < 16; m <<= 1) {
    #pragma unroll
    for (int r = 0; r < 8; r++) {
      float ob1 = __shfl_xor(b1[r], m, 64);
      int   oi1 = __shfl_xor(i1[r], m, 64);
      float ob2 = __shfl_xor(b2[r], m, 64);
      bool take = (ob1 < b1[r]) || (ob1 == b1[r] && oi1 < i1[r]);
      float loser = take ? b1[r] : ob1;
      if (take) { b1[r] = ob1; i1[r] = oi1; }
      b2[r] = fminf(fminf(b2[r], ob2), loser);
    }
  }

  if (tx == 0) {
    #pragma unroll
    for (int r = 0; r < 8; r++) {
      int fl = (b2[r] - b1[r] <= EPS) ? FLAGB : 0;
      idxs[ty * 8 + r] = i1[r] | fl;
    }
  }
  __syncthreads();

  // ---- exact fp64 rescue for uncertain rows (rare); no static-LDS intrinsics
  {
    bool pred = (tid < BM) && (idxs[tid] & FLAGB);
    unsigned long long bal = __ballot(pred);
    if (lane == 0) flags[wv] = (bal != 0ull) ? 1 : 0;
  }
  __syncthreads();
  int anyflag = flags[0] | flags[1] | flags[2] | flags[3];
  if (anyflag) {
    for (int row = 0; row < BM; row++) {
      if (!(idxs[row] & FLAGB)) continue;          // uniform branch
      double dot[4] = {0.0, 0.0, 0.0, 0.0};
      for (int d = 0; d < DIM; d++) {
        double a = (double)A[d * BM + row];        // LDS broadcast
        #pragma unroll
        for (int c = 0; c < 4; c++)
          dot[c] = fma(a, (double)ETq[(size_t)d * KC + tid + c * 256], dot[c]);
      }
      double bs = 1e300; int bk = 0;
      #pragma unroll
      for (int c = 0; c < 4; c++) {
        int k = tid + c * 256;
        double s = fma(-2.0, dot[c], cq64[k]);
        if (s < bs || (s == bs && k < bk)) { bs = s; bk = k; }
      }
      #pragma unroll
      for (int m = 1; m < 64; m <<= 1) {
        double ob = __shfl_xor(bs, m, 64);
        int    ok = __shfl_xor(bk, m, 64);
        if (ob < bs || (ob == bs && ok < bk)) { bs = ob; bk = ok; }
      }
      if (lane == 0) { redd[wv] = bs; redi[wv] = bk; }
      __syncthreads();
      if (tid == 0) {
        double fb = redd[0]; int fk = redi[0];
        #pragma unroll
        for (int w = 1; w < 4; w++) {
          if (redd[w] < fb || (redd[w] == fb && redi[w] < fk)) { fb = redd[w]; fk = redi[w]; }
        }
        idxs[row] = fk;                            // flag cleared
      }
      __syncthreads();
    }
  }

  // ---- fused update: gather q = E[idx], r_new = r_old - q, loss += (q-r_old)^2
  {
    int row = tid >> 1, h = tid & 1;
    int kidx = idxs[row] & 1023;
    if (h == 0) oidx[(rowbase + row) * 4 + st] = (float)kidx;
    const float4* e4 = (const float4*)(Eq + (size_t)kidx * DIM + h * 64);
    float4* ro = (float4*)(rout + (rowbase + row) * DIM + h * 64);
    float lsum = 0.f;
    #pragma unroll
    for (int i = 0; i < 16; i++) {
      float4 ev = e4[i];
      int d0 = h * 64 + i * 4;
      float r0 = A[(d0 + 0) * BM + row];
      float r1 = A[(d0 + 1) * BM + row];
      float r2 = A[(d0 + 2) * BM + row];
      float r3 = A[(d0 + 3) * BM + row];
      float d0v = r0 - ev.x, d1v = r1 - ev.y, d2v = r2 - ev.z, d3v = r3 - ev.w;
      lsum = fmaf(d0v, d0v, lsum);
      lsum = fmaf(d1v, d1v, lsum);
      lsum = fmaf(d2v, d2v, lsum);
      lsum = fmaf(d3v, d3v, lsum);
      ro[i] = make_float4(d0v, d1v, d2v, d3v);
    }
    #pragma unroll
    for (int m = 1; m < 64; m <<= 1) lsum += __shfl_xor(lsum, m, 64);
    if (lane == 0) redf[wv] = lsum;
    __syncthreads();
    if (tid == 0) lpart[st * (N_ROWS / BM) + blockIdx.x] =
        redf[0] + redf[1] + redf[2] + redf[3];
  }
}

// x_q = x - r, in place (r lives in the x_q region of d_out)
__global__ void k_xq(const float* __restrict__ x, float* __restrict__ xq) {
  size_t i = (size_t)blockIdx.x * blockDim.x + threadIdx.x;
  size_t stride = (size_t)gridDim.x * blockDim.x;
  const float4* x4 = (const float4*)x;
  float4* o4 = (float4*)xq;
  size_t n4 = (size_t)N_ROWS * DIM / 4;
  for (size_t k = i; k < n4; k += stride) {
    float4 a = x4[k], b = o4[k];
    o4[k] = make_float4(a.x - b.x, a.y - b.y, a.z - b.z, a.w - b.w);
  }
}

__global__ void k_loss(const float* __restrict__ part, float* __restrict__ o) {
  __shared__ float red[4];
  int tid = threadIdx.x;
  float s = 0.f;
  for (int i = tid; i < QST * (N_ROWS / BM); i += NTH) s += part[i];
  #pragma unroll
  for (int m = 1; m < 64; m <<= 1) s += __shfl_xor(s, m, 64);
  if ((tid & 63) == 0) red[tid >> 6] = s;
  __syncthreads();
  if (tid == 0)
    o[0] = (red[0] + red[1] + red[2] + red[3]) *
           (1.25f / ((float)QST * (float)N_ROWS * (float)DIM));
}

extern "C" void kernel_launch(void* const* d_in, const int* in_sizes, int n_in,
                              void* d_out, int out_size, void* d_ws, size_t ws_size,
                              hipStream_t stream) {
  const float* x  = (const float*)d_in[0];
  const float* cb = (const float*)d_in[1];
  float* out = (float*)d_out;
  float* ws  = (float*)d_ws;

  float*  r      = out;                                   // residual in x_q region
  float*  ET     = ws;                                    // Q*D*K transposed (2 MB)
  double* cvec64 = (double*)(ET + (size_t)QST * DIM * KC);
  float*  cvec32 = (float*)(cvec64 + (size_t)QST * KC);
  float*  part   = cvec32 + (size_t)QST * KC;             // Q*(N/BM) loss partials

  float* out_loss = out + (size_t)N_ROWS * DIM;
  float* out_idx  = out_loss + 1;

  // A tile (64 KB) + idxs/red/flags scratch; NO static LDS anywhere in k_stage
  static const size_t SMEM = (A_FLOATS + 152) * sizeof(float); // 66144 B
  hipFuncSetAttribute(reinterpret_cast<const void*>(k_stage),
                      hipFuncAttributeMaxDynamicSharedMemorySize, (int)SMEM);

  k_prep<<<(QST * KC + NTH - 1) / NTH, NTH, 0, stream>>>(cb, ET, cvec64, cvec32);

  for (int s = 0; s < QST; s++) {
    const float* rin = (s == 0) ? x : r;
    k_stage<<<N_ROWS / BM, NTH, SMEM, stream>>>(s, rin, r, cb, ET, cvec64, cvec32,
                                                out_idx, part);
  }

  k_xq<<<2048, NTH, 0, stream>>>(x, out);
  k_loss<<<1, NTH, 0, stream>>>(part, out_loss);
}

// Round 5
// 1053.810 us; speedup vs baseline: 2.7329x; 2.7329x over previous
//
#include <hip/hip_runtime.h>

#define N_ROWS 131072
#define DIM    128
#define QST    4
#define KC     1024
#define BM     128     // rows per workgroup (4 waves x 32 rows)
#define NTH    256
#define EPS    6e-3f   // certified fp16-split argmin margin
#define FLAGB  (1 << 16)

typedef _Float16 h8  __attribute__((ext_vector_type(8)));
typedef float    fx4 __attribute__((ext_vector_type(4)));

#define MFMA16(a, b, c) __builtin_amdgcn_mfma_f32_16x16x32_f16((a), (b), (c), 0, 0, 0)

// Pack codebooks into MFMA B-fragments (fp16 hi/lo), plus fp32 ET for rescue
// and ||E||^2 in fp64 (+fp32 copy).
// packB layout (halfs): [q][cc(8)][ct(8)][kt(4)][h(2)][lane(64)][j(8)]
__global__ void k_prep(const float* __restrict__ cb, float* __restrict__ ET,
                       double* __restrict__ cvec64, float* __restrict__ cvec32,
                       _Float16* __restrict__ packB) {
  int gid = blockIdx.x * blockDim.x + threadIdx.x;
  if (gid >= QST * KC) return;
  int q = gid >> 10, code = gid & (KC - 1);
  int cc = code >> 7, ct = (code >> 4) & 7, n = code & 15;
  const float* e = cb + ((size_t)q * KC + code) * DIM;
  double s = 0.0;
  for (int d = 0; d < DIM; d++) {
    float v = e[d];
    s = fma((double)v, (double)v, s);
    ET[((size_t)q * DIM + d) * KC + code] = v;
    int kt = d >> 5, g = (d >> 3) & 3, j = d & 7;
    int lane = g * 16 + n;
    size_t base = ((size_t)(((q * 8 + cc) * 8 + ct) * 4 + kt) * 2) * 512 + lane * 8 + j;
    _Float16 hh = (_Float16)v;
    packB[base]       = hh;                          // hi
    packB[base + 512] = (_Float16)(v - (float)hh);   // lo
  }
  cvec64[q * KC + code] = s;
  cvec32[q * KC + code] = (float)s;
}

__global__ __launch_bounds__(NTH, 2) void k_stage(
    int st, const float* rin, float* rout,
    const float* __restrict__ cb, const float* __restrict__ ET,
    const double* __restrict__ cvec64, const float* __restrict__ cvec32,
    const _Float16* __restrict__ packB,
    float* __restrict__ oidx, float* __restrict__ lpart)
{
  __shared__ int    idxs[BM];
  __shared__ double redd[4];
  __shared__ int    redi[4];
  __shared__ float  redf[4];
  __shared__ int    flags[4];

  const int tid = threadIdx.x;
  const int lane = tid & 63, wv = tid >> 6;
  const int tx = tid & 15;
  const size_t rowbase = (size_t)blockIdx.x * BM;

  // ---- A-fragments: 2 rowtiles x 4 ktiles, fp16 hi/lo, straight from global
  h8 ah[2][4], al[2][4];
  #pragma unroll
  for (int rt = 0; rt < 2; rt++) {
    const float* rowp = rin + (rowbase + wv * 32 + rt * 16 + (lane & 15)) * (size_t)DIM
                        + ((lane >> 4) * 8);
    #pragma unroll
    for (int kt = 0; kt < 4; kt++) {
      float4 f0 = *(const float4*)(rowp + kt * 32);
      float4 f1 = *(const float4*)(rowp + kt * 32 + 4);
      float vv[8] = {f0.x, f0.y, f0.z, f0.w, f1.x, f1.y, f1.z, f1.w};
      #pragma unroll
      for (int j = 0; j < 8; j++) {
        _Float16 hh = (_Float16)vv[j];
        ah[rt][kt][j] = hh;
        al[rt][kt][j] = (_Float16)(vv[j] - (float)hh);
      }
    }
  }

  const float*    ETq  = ET + (size_t)st * DIM * KC;
  const double*   cq64 = cvec64 + st * KC;
  const float*    cq32 = cvec32 + st * KC;
  const float*    Eq   = cb + (size_t)st * KC * DIM;
  const _Float16* PB   = packB + (size_t)st * 262144;

  float b1[8], b2[8];
  int   i1[8];
  #pragma unroll
  for (int i = 0; i < 8; i++) { b1[i] = 3.4e38f; b2[i] = 3.4e38f; i1[i] = 0; }

  const fx4 zero4 = {0.f, 0.f, 0.f, 0.f};

  #pragma unroll 1
  for (int cc = 0; cc < 8; cc++) {
    __syncthreads();   // keep waves lockstep so B-frag stream stays L1-hot
    fx4 acc[2][8];
    #pragma unroll
    for (int rt = 0; rt < 2; rt++)
      #pragma unroll
      for (int ct = 0; ct < 8; ct++) acc[rt][ct] = zero4;

    #pragma unroll
    for (int kt = 0; kt < 4; kt++) {
      #pragma unroll
      for (int cp = 0; cp < 4; cp++) {
        const _Float16* p0 = PB + (size_t)((cc * 8 + 2 * cp) * 4 + kt) * 1024 + lane * 8;
        const _Float16* p1 = PB + (size_t)((cc * 8 + 2 * cp + 1) * 4 + kt) * 1024 + lane * 8;
        h8 bh0 = *(const h8*)p0;
        h8 bl0 = *(const h8*)(p0 + 512);
        h8 bh1 = *(const h8*)p1;
        h8 bl1 = *(const h8*)(p1 + 512);
        int c0 = 2 * cp, c1 = 2 * cp + 1;
        // interleave 4 independent accumulators, 3 products each
        acc[0][c0] = MFMA16(ah[0][kt], bh0, acc[0][c0]);
        acc[1][c0] = MFMA16(ah[1][kt], bh0, acc[1][c0]);
        acc[0][c1] = MFMA16(ah[0][kt], bh1, acc[0][c1]);
        acc[1][c1] = MFMA16(ah[1][kt], bh1, acc[1][c1]);
        acc[0][c0] = MFMA16(al[0][kt], bh0, acc[0][c0]);
        acc[1][c0] = MFMA16(al[1][kt], bh0, acc[1][c0]);
        acc[0][c1] = MFMA16(al[0][kt], bh1, acc[0][c1]);
        acc[1][c1] = MFMA16(al[1][kt], bh1, acc[1][c1]);
        acc[0][c0] = MFMA16(ah[0][kt], bl0, acc[0][c0]);
        acc[1][c0] = MFMA16(ah[1][kt], bl0, acc[1][c0]);
        acc[0][c1] = MFMA16(ah[0][kt], bl1, acc[0][c1]);
        acc[1][c1] = MFMA16(ah[1][kt], bl1, acc[1][c1]);
      }
    }

    // ---- scores; per-row top-2. C layout: col=lane&15, row=(lane>>4)*4+reg
    #pragma unroll
    for (int ct = 0; ct < 8; ct++) {
      float cvv = cq32[cc * 128 + ct * 16 + tx];
      int code = cc * 128 + ct * 16 + tx;
      #pragma unroll
      for (int rt = 0; rt < 2; rt++) {
        #pragma unroll
        for (int j = 0; j < 4; j++) {
          float sc = fmaf(-2.f, acc[rt][ct][j], cvv);
          int r = rt * 4 + j;
          if (sc < b1[r]) { b2[r] = b1[r]; b1[r] = sc; i1[r] = code; }
          else            { b2[r] = fminf(b2[r], sc); }
        }
      }
    }
  }

  // ---- cross-lane top-2 reduce over the 16 lanes sharing each row
  #pragma unroll
  for (int m = 1; m < 16; m <<= 1) {
    #pragma unroll
    for (int r = 0; r < 8; r++) {
      float ob1 = __shfl_xor(b1[r], m, 64);
      int   oi1 = __shfl_xor(i1[r], m, 64);
      float ob2 = __shfl_xor(b2[r], m, 64);
      bool take = (ob1 < b1[r]) || (ob1 == b1[r] && oi1 < i1[r]);
      float loser = take ? b1[r] : ob1;
      if (take) { b1[r] = ob1; i1[r] = oi1; }
      b2[r] = fminf(fminf(b2[r], ob2), loser);
    }
  }

  if (tx == 0) {
    int g = lane >> 4;
    #pragma unroll
    for (int rt = 0; rt < 2; rt++)
      #pragma unroll
      for (int j = 0; j < 4; j++) {
        int r = rt * 4 + j;
        int fl = (b2[r] - b1[r] <= EPS) ? FLAGB : 0;
        idxs[wv * 32 + rt * 16 + g * 4 + j] = i1[r] | fl;
      }
  }
  __syncthreads();

  // ---- exact fp64 rescue for uncertain rows (rare)
  {
    bool pred = (tid < BM) && (idxs[tid] & FLAGB);
    unsigned long long bal = __ballot(pred);
    if (lane == 0) flags[wv] = (bal != 0ull) ? 1 : 0;
  }
  __syncthreads();
  int anyflag = flags[0] | flags[1] | flags[2] | flags[3];
  if (anyflag) {
    for (int row = 0; row < BM; row++) {
      if (!(idxs[row] & FLAGB)) continue;          // uniform branch
      const float* rrow = rin + (rowbase + row) * (size_t)DIM;
      double dot[4] = {0.0, 0.0, 0.0, 0.0};
      for (int d = 0; d < DIM; d++) {
        double a = (double)rrow[d];                // broadcast load
        #pragma unroll
        for (int c = 0; c < 4; c++)
          dot[c] = fma(a, (double)ETq[(size_t)d * KC + tid + c * 256], dot[c]);
      }
      double bs = 1e300; int bk = 0;
      #pragma unroll
      for (int c = 0; c < 4; c++) {
        int k = tid + c * 256;
        double s = fma(-2.0, dot[c], cq64[k]);
        if (s < bs || (s == bs && k < bk)) { bs = s; bk = k; }
      }
      #pragma unroll
      for (int m = 1; m < 64; m <<= 1) {
        double ob = __shfl_xor(bs, m, 64);
        int    ok = __shfl_xor(bk, m, 64);
        if (ob < bs || (ob == bs && ok < bk)) { bs = ob; bk = ok; }
      }
      if (lane == 0) { redd[wv] = bs; redi[wv] = bk; }
      __syncthreads();
      if (tid == 0) {
        double fb = redd[0]; int fk = redi[0];
        #pragma unroll
        for (int w = 1; w < 4; w++) {
          if (redd[w] < fb || (redd[w] == fb && redi[w] < fk)) { fb = redd[w]; fk = redi[w]; }
        }
        idxs[row] = fk;                            // flag cleared
      }
      __syncthreads();
    }
  }

  // ---- fused update: gather q=E[idx], r_new = r_old - q, loss += (q-r_old)^2
  {
    int row = tid >> 1, h = tid & 1;
    int kidx = idxs[row] & 1023;
    if (h == 0) oidx[(rowbase + row) * 4 + st] = (float)kidx;
    const float4* e4 = (const float4*)(Eq + (size_t)kidx * DIM + h * 64);
    const float4* r4 = (const float4*)(rin + (rowbase + row) * (size_t)DIM + h * 64);
    float4*       ro = (float4*)(rout + (rowbase + row) * (size_t)DIM + h * 64);
    float lsum = 0.f;
    #pragma unroll
    for (int i = 0; i < 16; i++) {
      float4 rv = r4[i];
      float4 ev = e4[i];
      float d0v = rv.x - ev.x, d1v = rv.y - ev.y, d2v = rv.z - ev.z, d3v = rv.w - ev.w;
      lsum = fmaf(d0v, d0v, lsum);
      lsum = fmaf(d1v, d1v, lsum);
      lsum = fmaf(d2v, d2v, lsum);
      lsum = fmaf(d3v, d3v, lsum);
      ro[i] = make_float4(d0v, d1v, d2v, d3v);
    }
    #pragma unroll
    for (int m = 1; m < 64; m <<= 1) lsum += __shfl_xor(lsum, m, 64);
    if (lane == 0) redf[wv] = lsum;
    __syncthreads();
    if (tid == 0) lpart[st * (N_ROWS / BM) + blockIdx.x] =
        redf[0] + redf[1] + redf[2] + redf[3];
  }
}

// x_q = x - r, in place (r lives in the x_q region of d_out)
__global__ void k_xq(const float* __restrict__ x, float* __restrict__ xq) {
  size_t i = (size_t)blockIdx.x * blockDim.x + threadIdx.x;
  size_t stride = (size_t)gridDim.x * blockDim.x;
  const float4* x4 = (const float4*)x;
  float4* o4 = (float4*)xq;
  size_t n4 = (size_t)N_ROWS * DIM / 4;
  for (size_t k = i; k < n4; k += stride) {
    float4 a = x4[k], b = o4[k];
    o4[k] = make_float4(a.x - b.x, a.y - b.y, a.z - b.z, a.w - b.w);
  }
}

__global__ void k_loss(const float* __restrict__ part, float* __restrict__ o) {
  __shared__ float red[4];
  int tid = threadIdx.x;
  float s = 0.f;
  for (int i = tid; i < QST * (N_ROWS / BM); i += NTH) s += part[i];
  #pragma unroll
  for (int m = 1; m < 64; m <<= 1) s += __shfl_xor(s, m, 64);
  if ((tid & 63) == 0) red[tid >> 6] = s;
  __syncthreads();
  if (tid == 0)
    o[0] = (red[0] + red[1] + red[2] + red[3]) *
           (1.25f / ((float)QST * (float)N_ROWS * (float)DIM));
}

extern "C" void kernel_launch(void* const* d_in, const int* in_sizes, int n_in,
                              void* d_out, int out_size, void* d_ws, size_t ws_size,
                              hipStream_t stream) {
  const float* x  = (const float*)d_in[0];
  const float* cb = (const float*)d_in[1];
  float* out = (float*)d_out;
  float* ws  = (float*)d_ws;

  float*    r      = out;                                   // residual in x_q region
  float*    ET     = ws;                                    // Q*D*K fp32 (2 MB)
  double*   cvec64 = (double*)(ET + (size_t)QST * DIM * KC);
  float*    cvec32 = (float*)(cvec64 + (size_t)QST * KC);
  float*    part   = cvec32 + (size_t)QST * KC;             // Q*1024 partials
  _Float16* packB  = (_Float16*)(part + (size_t)QST * (N_ROWS / BM)); // 2 MB frags

  float* out_loss = out + (size_t)N_ROWS * DIM;
  float* out_idx  = out_loss + 1;

  k_prep<<<(QST * KC + NTH - 1) / NTH, NTH, 0, stream>>>(cb, ET, cvec64, cvec32, packB);

  for (int s = 0; s < QST; s++) {
    const float* rin = (s == 0) ? x : r;
    k_stage<<<N_ROWS / BM, NTH, 0, stream>>>(s, rin, r, cb, ET, cvec64, cvec32,
                                             packB, out_idx, part);
  }

  k_xq<<<2048, NTH, 0, stream>>>(x, out);
  k_loss<<<1, NTH, 0, stream>>>(part, out_loss);
}

// Round 6
// 677.432 us; speedup vs baseline: 4.2512x; 1.5556x over previous
//
#include <hip/hip_runtime.h>

#define N_ROWS 131072
#define DIM    128
#define QST    4
#define KC     1024
#define BM     128     // rows per workgroup (4 waves x 32 rows)
#define NTH    256
#define EPS    6e-3f   // certified fp16-split argmin margin
#define FLAGB  (1 << 16)

typedef _Float16 h8  __attribute__((ext_vector_type(8)));
typedef float    fx4 __attribute__((ext_vector_type(4)));

typedef __attribute__((address_space(3))) void lds_void;
typedef const __attribute__((address_space(1))) void glb_void;

#define MFMA16(a, b, c) __builtin_amdgcn_mfma_f32_16x16x32_f16((a), (b), (c), 0, 0, 0)

// packB halfs layout: [q][ch(16)][ctl(4)][kt(4)][hl(2)][lane(64)][j(8)]
// -> each 32 KB chunk stages linearly into LDS.
__global__ void k_prep(const float* __restrict__ cb,
                       double* __restrict__ cvec64, float* __restrict__ cvec32,
                       _Float16* __restrict__ packB) {
  int gid = blockIdx.x * blockDim.x + threadIdx.x;
  if (gid >= QST * KC) return;
  int q = gid >> 10, code = gid & (KC - 1);
  int ch = code >> 6, ctl = (code >> 4) & 3, n = code & 15;
  const float* e = cb + ((size_t)q * KC + code) * DIM;
  double s = 0.0;
  for (int d = 0; d < DIM; d++) {
    float v = e[d];
    s = fma((double)v, (double)v, s);
    int kt = d >> 5, g = (d >> 3) & 3, j = d & 7;
    int lane = g * 16 + n;
    size_t base = ((size_t)q * 16 + ch) * 16384
                + (size_t)((ctl * 4 + kt) * 2) * 512 + lane * 8 + j;
    _Float16 hh = (_Float16)v;
    packB[base]       = hh;                          // hi
    packB[base + 512] = (_Float16)(v - (float)hh);   // lo
  }
  cvec64[q * KC + code] = s;
  cvec32[q * KC + code] = (float)s;
}

__global__ __launch_bounds__(NTH, 2) void k_stage(
    int st, const float* rin, float* rout, const float* __restrict__ x,
    const float* __restrict__ cb,
    const double* __restrict__ cvec64, const float* __restrict__ cvec32,
    const _Float16* __restrict__ packB,
    float* __restrict__ oidx, float* __restrict__ lpart, int final_stage)
{
  extern __shared__ float smem[];
  _Float16* Bl    = (_Float16*)smem;              // [2][16384] halfs = 64 KB
  int*      idxs  = (int*)(smem + 16384);         // 128 ints
  double*   redd  = (double*)(smem + 16384 + 128);// 4 doubles (8B aligned)
  int*      redi  = (int*)(smem + 16384 + 136);
  float*    redf  = smem + 16384 + 140;
  int*      flags = (int*)(smem + 16384 + 144);

  const int tid = threadIdx.x;
  const int lane = tid & 63, wv = tid >> 6;
  const int tx = tid & 15;
  const size_t rowbase = (size_t)blockIdx.x * BM;

  // ---- A-fragments: 2 rowtiles x 4 ktiles, fp16 hi/lo, straight from global
  h8 ah[2][4], al[2][4];
  #pragma unroll
  for (int rt = 0; rt < 2; rt++) {
    const float* rowp = rin + (rowbase + wv * 32 + rt * 16 + (lane & 15)) * (size_t)DIM
                        + ((lane >> 4) * 8);
    #pragma unroll
    for (int kt = 0; kt < 4; kt++) {
      float4 f0 = *(const float4*)(rowp + kt * 32);
      float4 f1 = *(const float4*)(rowp + kt * 32 + 4);
      float vv[8] = {f0.x, f0.y, f0.z, f0.w, f1.x, f1.y, f1.z, f1.w};
      #pragma unroll
      for (int j = 0; j < 8; j++) {
        _Float16 hh = (_Float16)vv[j];
        ah[rt][kt][j] = hh;
        al[rt][kt][j] = (_Float16)(vv[j] - (float)hh);
      }
    }
  }

  const double*   cq64 = cvec64 + st * KC;
  const float*    cq32 = cvec32 + st * KC;
  const float*    Eq   = cb + (size_t)st * KC * DIM;
  const _Float16* PBq  = packB + (size_t)st * 262144;

  // stage one 32 KB chunk (linear): per wave 8 x (64 lanes x 16 B)
  auto stageB = [&](int ch, int buf) {
    const _Float16* src = PBq + (size_t)ch * 16384 + wv * 4096 + lane * 8;
    _Float16* dst = Bl + buf * 16384 + wv * 4096;   // wave-uniform base
    #pragma unroll
    for (int i = 0; i < 8; i++)
      __builtin_amdgcn_global_load_lds((glb_void*)(src + i * 512),
                                       (lds_void*)(dst + i * 512), 16, 0, 0);
  };

  float b1[8], b2[8];
  int   i1[8];
  #pragma unroll
  for (int i = 0; i < 8; i++) { b1[i] = 3.4e38f; b2[i] = 3.4e38f; i1[i] = 0; }

  const fx4 zero4 = {0.f, 0.f, 0.f, 0.f};

  stageB(0, 0);
  __syncthreads();   // vmcnt(0)+lgkmcnt(0) drain: chunk 0 ready

  #pragma unroll 1
  for (int ch = 0; ch < 16; ch++) {
    if (ch < 15) stageB(ch + 1, (ch + 1) & 1);      // prefetch next chunk

    const _Float16* Bb = Bl + (ch & 1) * 16384;
    fx4 acc[2][4];
    #pragma unroll
    for (int rt = 0; rt < 2; rt++)
      #pragma unroll
      for (int ct = 0; ct < 4; ct++) acc[rt][ct] = zero4;

    #pragma unroll
    for (int kt = 0; kt < 4; kt++) {
      #pragma unroll
      for (int ct = 0; ct < 4; ct++) {
        const _Float16* p = Bb + (size_t)((ct * 4 + kt) * 2) * 512 + lane * 8;
        h8 bh = *(const h8*)p;
        h8 bl = *(const h8*)(p + 512);
        acc[0][ct] = MFMA16(ah[0][kt], bh, acc[0][ct]);
        acc[1][ct] = MFMA16(ah[1][kt], bh, acc[1][ct]);
        acc[0][ct] = MFMA16(al[0][kt], bh, acc[0][ct]);
        acc[1][ct] = MFMA16(al[1][kt], bh, acc[1][ct]);
        acc[0][ct] = MFMA16(ah[0][kt], bl, acc[0][ct]);
        acc[1][ct] = MFMA16(ah[1][kt], bl, acc[1][ct]);
      }
    }

    // ---- scores; per-row top-2. C layout: col=lane&15, row=(lane>>4)*4+reg
    #pragma unroll
    for (int ct = 0; ct < 4; ct++) {
      int code = ch * 64 + ct * 16 + tx;
      float cvv = cq32[code];
      #pragma unroll
      for (int rt = 0; rt < 2; rt++) {
        #pragma unroll
        for (int j = 0; j < 4; j++) {
          float sc = fmaf(-2.f, acc[rt][ct][j], cvv);
          int r = rt * 4 + j;
          if (sc < b1[r]) { b2[r] = b1[r]; b1[r] = sc; i1[r] = code; }
          else            { b2[r] = fminf(b2[r], sc); }
        }
      }
    }
    __syncthreads();   // chunk ch consumed; prefetch (vmcnt) drained
  }

  // ---- cross-lane top-2 reduce over the 16 lanes sharing each row
  #pragma unroll
  for (int m = 1; m < 16; m <<= 1) {
    #pragma unroll
    for (int r = 0; r < 8; r++) {
      float ob1 = __shfl_xor(b1[r], m, 64);
      int   oi1 = __shfl_xor(i1[r], m, 64);
      float ob2 = __shfl_xor(b2[r], m, 64);
      bool take = (ob1 < b1[r]) || (ob1 == b1[r] && oi1 < i1[r]);
      float loser = take ? b1[r] : ob1;
      if (take) { b1[r] = ob1; i1[r] = oi1; }
      b2[r] = fminf(fminf(b2[r], ob2), loser);
    }
  }

  if (tx == 0) {
    int g = lane >> 4;
    #pragma unroll
    for (int rt = 0; rt < 2; rt++)
      #pragma unroll
      for (int j = 0; j < 4; j++) {
        int r = rt * 4 + j;
        int fl = (b2[r] - b1[r] <= EPS) ? FLAGB : 0;
        idxs[wv * 32 + rt * 16 + g * 4 + j] = i1[r] | fl;
      }
  }
  __syncthreads();

  // ---- exact fp64 rescue for uncertain rows (rare); reads codebook rows
  {
    bool pred = (tid < BM) && (idxs[tid] & FLAGB);
    unsigned long long bal = __ballot(pred);
    if (lane == 0) flags[wv] = (bal != 0ull) ? 1 : 0;
  }
  __syncthreads();
  int anyflag = flags[0] | flags[1] | flags[2] | flags[3];
  if (anyflag) {
    for (int row = 0; row < BM; row++) {
      if (!(idxs[row] & FLAGB)) continue;          // uniform branch
      const float* rrow = rin + (rowbase + row) * (size_t)DIM;
      double dot[4] = {0.0, 0.0, 0.0, 0.0};
      for (int d = 0; d < DIM; d++) {
        double a = (double)rrow[d];                // broadcast load
        #pragma unroll
        for (int c = 0; c < 4; c++)
          dot[c] = fma(a, (double)Eq[(size_t)(tid + c * 256) * DIM + d], dot[c]);
      }
      double bs = 1e300; int bk = 0;
      #pragma unroll
      for (int c = 0; c < 4; c++) {
        int k = tid + c * 256;
        double s = fma(-2.0, dot[c], cq64[k]);
        if (s < bs || (s == bs && k < bk)) { bs = s; bk = k; }
      }
      #pragma unroll
      for (int m = 1; m < 64; m <<= 1) {
        double ob = __shfl_xor(bs, m, 64);
        int    ok = __shfl_xor(bk, m, 64);
        if (ob < bs || (ob == bs && ok < bk)) { bs = ob; bk = ok; }
      }
      if (lane == 0) { redd[wv] = bs; redi[wv] = bk; }
      __syncthreads();
      if (tid == 0) {
        double fb = redd[0]; int fk = redi[0];
        #pragma unroll
        for (int w = 1; w < 4; w++) {
          if (redd[w] < fb || (redd[w] == fb && redi[w] < fk)) { fb = redd[w]; fk = redi[w]; }
        }
        idxs[row] = fk;                            // flag cleared
      }
      __syncthreads();
    }
  }

  // ---- fused epilogue, fully coalesced flat writes:
  //      r_new = r_old - E[idx]; loss += (E[idx]-r_old)^2; last stage: out = x - r_new
  {
    float lsum = 0.f;
    #pragma unroll 1
    for (int it = 0; it < 16; it++) {
      int g = it * NTH + tid;
      int row = g >> 5, c4 = g & 31;
      int kidx = idxs[row] & 1023;
      if ((g & 31) == 0) oidx[(rowbase + row) * 4 + st] = (float)kidx;
      float4 ev = *(const float4*)(Eq + (size_t)kidx * DIM + c4 * 4);
      float4 rv = *(const float4*)(rin + (rowbase + row) * (size_t)DIM + c4 * 4);
      float4 dv = make_float4(rv.x - ev.x, rv.y - ev.y, rv.z - ev.z, rv.w - ev.w);
      lsum = fmaf(dv.x, dv.x, lsum);
      lsum = fmaf(dv.y, dv.y, lsum);
      lsum = fmaf(dv.z, dv.z, lsum);
      lsum = fmaf(dv.w, dv.w, lsum);
      float4 wv4 = dv;
      if (final_stage) {
        float4 xv = *(const float4*)(x + (rowbase + row) * (size_t)DIM + c4 * 4);
        wv4 = make_float4(xv.x - dv.x, xv.y - dv.y, xv.z - dv.z, xv.w - dv.w);
      }
      *(float4*)(rout + (rowbase + row) * (size_t)DIM + c4 * 4) = wv4;
    }
    #pragma unroll
    for (int m = 1; m < 64; m <<= 1) lsum += __shfl_xor(lsum, m, 64);
    if (lane == 0) redf[wv] = lsum;
    __syncthreads();
    if (tid == 0) lpart[st * (N_ROWS / BM) + blockIdx.x] =
        redf[0] + redf[1] + redf[2] + redf[3];
  }
}

__global__ void k_loss(const float* __restrict__ part, float* __restrict__ o) {
  __shared__ float red[4];
  int tid = threadIdx.x;
  float s = 0.f;
  for (int i = tid; i < QST * (N_ROWS / BM); i += NTH) s += part[i];
  #pragma unroll
  for (int m = 1; m < 64; m <<= 1) s += __shfl_xor(s, m, 64);
  if ((tid & 63) == 0) red[tid >> 6] = s;
  __syncthreads();
  if (tid == 0)
    o[0] = (red[0] + red[1] + red[2] + red[3]) *
           (1.25f / ((float)QST * (float)N_ROWS * (float)DIM));
}

extern "C" void kernel_launch(void* const* d_in, const int* in_sizes, int n_in,
                              void* d_out, int out_size, void* d_ws, size_t ws_size,
                              hipStream_t stream) {
  const float* x  = (const float*)d_in[0];
  const float* cb = (const float*)d_in[1];
  float* out = (float*)d_out;
  float* ws  = (float*)d_ws;

  float*    r      = out;                                   // residual in x_q region
  double*   cvec64 = (double*)ws;                           // Q*K fp64 ||E||^2
  float*    cvec32 = (float*)(cvec64 + (size_t)QST * KC);
  float*    part   = cvec32 + (size_t)QST * KC;             // Q*1024 partials
  _Float16* packB  = (_Float16*)(part + (size_t)QST * (N_ROWS / BM)); // 4 MB frags

  float* out_loss = out + (size_t)N_ROWS * DIM;
  float* out_idx  = out_loss + 1;

  static const size_t SMEM = (16384 + 160) * sizeof(float); // 66176 B
  hipFuncSetAttribute(reinterpret_cast<const void*>(k_stage),
                      hipFuncAttributeMaxDynamicSharedMemorySize, (int)SMEM);

  k_prep<<<(QST * KC + NTH - 1) / NTH, NTH, 0, stream>>>(cb, cvec64, cvec32, packB);

  for (int s = 0; s < QST; s++) {
    const float* rin = (s == 0) ? x : r;
    k_stage<<<N_ROWS / BM, NTH, SMEM, stream>>>(s, rin, r, x, cb, cvec64, cvec32,
                                                packB, out_idx, part,
                                                (s == QST - 1) ? 1 : 0);
  }

  k_loss<<<1, NTH, 0, stream>>>(part, out_loss);
}